// Round 10
// baseline (119.805 us; speedup 1.0000x reference)
//
#include <hip/hip_runtime.h>
#include <math.h>

#define S_LEN 1024
#define D_DIM 64
#define NBH   16
#define RPB   16
#define NSB   64           // 1024/16 -> grid 64x16 = 1024 blocks = 4/CU exactly
#define DPS   1024         // dpH row stride (halfs), XOR-swizzled banks

typedef unsigned short ushort_t;
typedef unsigned int uint_t;
typedef __attribute__((ext_vector_type(8))) _Float16 half8;  // 8 f16 (4 VGPRs)
typedef __attribute__((ext_vector_type(4))) short short4v;   // 8 B
typedef __attribute__((ext_vector_type(4))) float f32x4;

__device__ __forceinline__ ushort_t f16bits(float x) {
    _Float16 h = (_Float16)x;                 // RNE
    ushort_t b;
    __builtin_memcpy(&b, &h, 2);
    return b;
}
__device__ __forceinline__ float uniform_f(float x) {
    return __int_as_float(__builtin_amdgcn_readfirstlane(__float_as_int(x)));
}
__device__ __forceinline__ float fast_exp2(float x) {
#if __has_builtin(__builtin_amdgcn_exp2f)
    return __builtin_amdgcn_exp2f(x);         // v_exp_f32 (2^x)
#else
    return exp2f(x);
#endif
}
__device__ __forceinline__ half8 mk8(uint2 a, uint2 b) {
    union { uint_t u[4]; half8 h; } c;
    c.u[0] = a.x; c.u[1] = a.y; c.u[2] = b.x; c.u[3] = b.y;
    return c.h;
}
// One conv tap in ONE instruction: acc += f16half(xp) * w  (f32 accum/weight).
__device__ __forceinline__ float fmamix(int hi, uint_t xp, float w, float acc) {
    if (hi)
        asm("v_fma_mix_f32 %0, %1, %2, %0 op_sel:[1,0,0] op_sel_hi:[1,0,0]"
            : "+v"(acc) : "v"(xp), "s"(w));
    else
        asm("v_fma_mix_f32 %0, %1, %2, %0 op_sel:[0,0,0] op_sel_hi:[1,0,0]"
            : "+v"(acc) : "v"(xp), "s"(w));
    return acc;
}
__device__ __forceinline__ float fmamix3(int hi, uint_t xp, float w, float c) {
    float d;
    if (hi)
        asm("v_fma_mix_f32 %0, %1, %2, %3 op_sel:[1,0,0] op_sel_hi:[1,0,0]"
            : "=v"(d) : "v"(xp), "s"(w), "v"(c));
    else
        asm("v_fma_mix_f32 %0, %1, %2, %3 op_sel:[0,0,0] op_sel_hi:[1,0,0]"
            : "=v"(d) : "v"(xp), "s"(w), "v"(c));
    return d;
}

// ------------------------------ Prep (unchanged from R9) ---------------------
__global__ __launch_bounds__(256) void prep(
    const float* __restrict__ k, const float* __restrict__ v,
    const int* __restrict__ mask,
    ushort_t* __restrict__ kh, ushort_t* __restrict__ vh,
    unsigned* __restrict__ mw)
{
    __shared__ float Ls[64][65];
    const int tid = threadIdx.x;
    const int bx = blockIdx.x;
    if (bx < 512) {
        const int gid  = bx * 256 + tid;          // 0..131071
        const int bh   = gid >> 13;
        const int tile = (gid >> 7) & 63;
        const int ch   = (gid >> 6) & 1;
        const int lane = gid & 63;
        const int quad = lane >> 4, t15 = lane & 15;
        const float* src = k + ((size_t)bh * S_LEN + tile * 16 + t15) * D_DIM
                             + ch * 32 + quad * 8;
        float x[8];
        *(float4*)(x + 0) = *(const float4*)(src);
        *(float4*)(x + 4) = *(const float4*)(src + 4);
        ushort_t hv[8];
        #pragma unroll
        for (int i = 0; i < 8; ++i) hv[i] = f16bits(x[i] * 0.125f);
        *(short4v*)(kh + (size_t)gid * 8)     = *(short4v*)(hv);
        *(short4v*)(kh + (size_t)gid * 8 + 4) = *(short4v*)(hv + 4);
    } else if (bx < 768) {
        const int bi = bx - 512;
        const int tt = bi & 15, bh = bi >> 4;
        const float* vb = v + ((size_t)bh * S_LEN + tt * 64) * D_DIM;
        #pragma unroll
        for (int p = 0; p < 4; ++p) {
            int idx = p * 1024 + tid * 4;
            int r = idx >> 6, c = idx & 63;
            float4 x = *(const float4*)(vb + r * 64 + c);
            Ls[r][c] = x.x; Ls[r][c+1] = x.y; Ls[r][c+2] = x.z; Ls[r][c+3] = x.w;
        }
        __syncthreads();
        const int d = tid >> 2, c0 = (tid & 3) * 16;
        ushort_t hi[16];
        #pragma unroll
        for (int j = 0; j < 16; ++j) hi[j] = f16bits(Ls[c0 + j][d]);
        const int tb0 = tt * 8 + (c0 >> 3);
        const size_t o0 = (((size_t)bh * 128 + tb0) * 64 + d) * 8;
        const size_t o1 = (((size_t)bh * 128 + tb0 + 1) * 64 + d) * 8;
        *(short4v*)(vh + o0)     = *(short4v*)(hi);
        *(short4v*)(vh + o0 + 4) = *(short4v*)(hi + 4);
        *(short4v*)(vh + o1)     = *(short4v*)(hi + 8);
        *(short4v*)(vh + o1 + 4) = *(short4v*)(hi + 12);
    } else {
        const int gid = (bx - 768) * 256 + tid;    // 0..65535
        const int row = gid >> 5, wd = gid & 31;   // row = b*1024+s
        const int4* mp = (const int4*)(mask + (size_t)row * 1024 + wd * 32);
        unsigned bits = 0;
        #pragma unroll
        for (int p = 0; p < 8; ++p) {
            int4 qv = mp[p];
            bits |= (qv.x != 0 ? 1u : 0u) << (p * 4 + 0);
            bits |= (qv.y != 0 ? 1u : 0u) << (p * 4 + 1);
            bits |= (qv.z != 0 ? 1u : 0u) << (p * 4 + 2);
            bits |= (qv.w != 0 ? 1u : 0u) << (p * 4 + 3);
        }
        mw[(size_t)row * 32 + wd] = bits;
    }
}

// ---------- Fused: QK^T -> conv (v_fma_mix) -> PV ----------------------------
// RPB=16 -> grid 64x16 = 1024 blocks = EXACTLY 4 blocks/CU x 256 CU: the 160-
// block second generation (the ~2x tail at RPB=14) is eliminated.
// dp tile: 18 rows (s0-1 .. s0+16); rows 16/17 via a 2nd A-frag in the same
// tile loop (even lanes q[s0+15], odd q[s0+16]; quad0 writes C-rows 0/1).
// LDS 38912 B: dpH stride 1024 (pads dropped; aligned 2xb64+1xb32 window
// loads, zero-guards only at cg=0/255), XOR swizzle col^((row&7)<<2) on all
// dpH accesses (kills stride-1024 same-bank), oBuf lives in dpH rows 0/17
// (free during Phase C: P occupies rows 1..16), lsRow in dead mask region.
// All o-guards gone: every o=1..16 is active, every output row written once.
__global__ __launch_bounds__(512) void fused_qk_conv_av(
    const float* __restrict__ q,
    const ushort_t* __restrict__ kh, const unsigned* __restrict__ mw,
    const ushort_t* __restrict__ vh,
    const float* __restrict__ conv_w, const float* __restrict__ conv_b,
    const float* __restrict__ lin_w, const float* __restrict__ lin_b,
    float* __restrict__ out)
{
    __shared__ __align__(16) ushort_t dpH[18 * DPS];  // 36864 B
    __shared__ __align__(16) unsigned aux[16 * 32];   // 2048 B: mb, then lsRow

    const int st = blockIdx.x, bh = blockIdx.y;
    const int s0 = st * RPB;
    const int b  = bh >> 3;
    const int tid = threadIdx.x;
    const int wave = tid >> 6, lane = tid & 63;
    const int m = lane & 15, quad = lane >> 4;

    // mask bits -> aux as mb[o'][wd], o' = o-1, s = s0+o' (always in range)
    {
        const int o1 = tid >> 5, wd = tid & 31;
        aux[o1 * 32 + wd] = mw[((size_t)b * S_LEN + s0 + o1) * 32 + wd];
    }

    // ---------------- Phase A: QK rows 0..17 into swizzled dpH --------------
    const int sA = s0 - 1 + m;
    const int sQ = sA < 0 ? 0 : sA;                 // sA <= s0+14 <= 1022
    const float* qp = q + ((size_t)bh * S_LEN + sQ) * D_DIM + quad * 8;
    float qa[16];
    *(float4*)(qa + 0)  = *(const float4*)(qp + 0);
    *(float4*)(qa + 4)  = *(const float4*)(qp + 4);
    *(float4*)(qa + 8)  = *(const float4*)(qp + 32);
    *(float4*)(qa + 12) = *(const float4*)(qp + 36);
    half8 AH0, AH1;
    #pragma unroll
    for (int i = 0; i < 8; ++i) {
        AH0[i] = (_Float16)qa[i];          // 1/8 scale folded into kh
        AH1[i] = (_Float16)qa[8 + i];
    }
    // extra A-set for dp rows 16/17: even lanes s0+15, odd lanes s0+16
    const int sE = s0 + 15 + (m & 1);
    const int sEc = sE > S_LEN - 1 ? S_LEN - 1 : sE;
    const float* qp2 = q + ((size_t)bh * S_LEN + sEc) * D_DIM + quad * 8;
    float qb[16];
    *(float4*)(qb + 0)  = *(const float4*)(qp2 + 0);
    *(float4*)(qb + 4)  = *(const float4*)(qp2 + 4);
    *(float4*)(qb + 8)  = *(const float4*)(qp2 + 32);
    *(float4*)(qb + 12) = *(const float4*)(qp2 + 36);
    half8 AH2, AH3;
    #pragma unroll
    for (int i = 0; i < 8; ++i) {
        AH2[i] = (_Float16)qb[i];
        AH3[i] = (_Float16)qb[8 + i];
    }

    #pragma unroll
    for (int tt = 0; tt < 8; ++tt) {
        const int tile = wave * 8 + tt;
        const size_t kb = (((size_t)bh * 64 + tile) * 128 + lane) * 8;
        half8 KH0 = *(const half8*)(kh + kb);
        half8 KH1 = *(const half8*)(kh + kb + 512);
        f32x4 a = {0.f, 0.f, 0.f, 0.f};
        a = __builtin_amdgcn_mfma_f32_16x16x32_f16(AH0, KH0, a, 0, 0, 0);
        a = __builtin_amdgcn_mfma_f32_16x16x32_f16(AH1, KH1, a, 0, 0, 0);
        f32x4 a2 = {0.f, 0.f, 0.f, 0.f};
        a2 = __builtin_amdgcn_mfma_f32_16x16x32_f16(AH2, KH0, a2, 0, 0, 0);
        a2 = __builtin_amdgcn_mfma_f32_16x16x32_f16(AH3, KH1, a2, 0, 0, 0);
        const int col = tile * 16 + m;
        #pragma unroll
        for (int r = 0; r < 4; ++r) {
            const int row = quad * 4 + r;           // 0..15, s = s0-1+row
            const int s = s0 - 1 + row;
            const float v = (s >= 0) ? a[r] : 0.f;
            dpH[row * DPS + (col ^ ((row & 7) << 2))] = f16bits(v);
        }
        if (quad == 0) {                            // C-rows 0/1 -> dp 16/17
            #pragma unroll
            for (int r = 0; r < 2; ++r) {
                const int row = 16 + r;             // s = s0+15+r
                const float v = (s0 + 15 + r < S_LEN) ? a2[r] : 0.f;
                dpH[row * DPS + (col ^ ((row & 7) << 2))] = f16bits(v);
            }
        }
    }

    // hoisted uniform coefficients
    float w[36];
    #pragma unroll
    for (int i = 0; i < 36; ++i) w[i] = conv_w[i];
    const float L2E = 1.44269504088896341f;
    float cbV[4], aF[4], bF[4];
    #pragma unroll
    for (int f = 0; f < 4; ++f) {
        cbV[f] = conv_b[f];
        const float lwf = lin_w[f];
        aF[f] = uniform_f(0.505f * lwf * L2E);   // lr(x)=0.505x+0.495|x|
        bF[f] = uniform_f(0.495f * lwf * L2E);
    }
    const float lbE = uniform_f(lin_b[0] * L2E);

    __syncthreads();

    // ---------------- Phase B: conv (v_fma_mix) + mask + exp2 ---------------
    const int rh = tid >> 8, cg = tid & 255, c0 = cg * 4;
    uint2 Ps[8];           // packed f16 P: [pass*4 + jo] <-> o = rh*8+i+1
    #pragma unroll
    for (int pass = 0; pass < 2; ++pass) {
        const int obase = rh * 8 + pass * 4;        // window rows obase..+5
        uint_t wrw[6][4];  // halfs t = c0-2 .. c0+5 per row
        #pragma unroll
        for (int jj = 0; jj < 6; ++jj) {
            const int dr = obase + jj;              // 0..17, always valid
            const int sw = (dr & 7) << 2;
            const int base = dr * DPS;
            uint_t w0 = 0u;
            if (cg != 0)
                w0 = ((const uint2*)&dpH[base + ((c0 - 4) ^ sw)])->y;
            const uint2 mid = *(const uint2*)&dpH[base + (c0 ^ sw)];
            uint_t w3 = 0u;
            if (cg != 255)
                w3 = *(const uint_t*)&dpH[base + ((c0 + 4) ^ sw)];
            wrw[jj][0] = w0; wrw[jj][1] = mid.x;
            wrw[jj][2] = mid.y; wrw[jj][3] = w3;
        }
        // value at t = c0-1+p lives in word (p+1)>>1, half (p+1)&1
        #pragma unroll
        for (int jo = 0; jo < 4; ++jo) {
            const int o = obase + jo + 1;           // 1..16, ALWAYS active
            float pr[4] = {lbE, lbE, lbE, lbE};
            #pragma unroll
            for (int f = 0; f < 4; ++f) {
                const float* wf = w + f * 9;
                const float cbf = cbV[f];
                float acc[4];
                #pragma unroll
                for (int c = 0; c < 4; ++c) {
                    const int idx = c + 1;
                    acc[c] = fmamix3(idx & 1, wrw[jo][idx >> 1], wf[0], cbf);
                }
                #pragma unroll
                for (int t = 1; t < 9; ++t) {
                    const int dr = t / 3, dc = t % 3;
                    #pragma unroll
                    for (int c = 0; c < 4; ++c) {
                        const int idx = c + dc + 1;
                        acc[c] = fmamix(idx & 1, wrw[jo + dr][idx >> 1],
                                        wf[t], acc[c]);
                    }
                }
                const float af = aF[f], bf = bF[f];
                #pragma unroll
                for (int c = 0; c < 4; ++c) {
                    pr[c] = fmaf(af, acc[c], pr[c]);
                    pr[c] = fmaf(bf, fabsf(acc[c]), pr[c]);  // abs = mod
                }
            }
            const unsigned word = aux[(o - 1) * 32 + (cg >> 3)];
            const unsigned nib  = (word >> ((cg & 7) * 4)) & 0xFu;
            float pv[4];
            #pragma unroll
            for (int c = 0; c < 4; ++c) {
                const float pe = ((nib >> c) & 1u) ? pr[c] : -1e30f;
                pv[c] = fast_exp2(pe);              // exp(pre) == 2^(pre*L2E)
            }
            Ps[pass * 4 + jo].x =
                (uint_t)f16bits(pv[0]) | ((uint_t)f16bits(pv[1]) << 16);
            Ps[pass * 4 + jo].y =
                (uint_t)f16bits(pv[2]) | ((uint_t)f16bits(pv[3]) << 16);
        }
    }
    __syncthreads();   // all dp reads done -> safe to overwrite rows 1..16

    // write P in place: row o (1..16), col t at swizzled idx
    #pragma unroll
    for (int i = 0; i < 8; ++i) {
        const int o = rh * 8 + i + 1;
        *(uint2*)&dpH[o * DPS + (c0 ^ ((o & 7) << 2))] = Ps[i];
    }
    __syncthreads();

    // ---------------- Phase C: PV + MFMA row sums ---------------------------
    const int d0 = (wave & 3) * 16;
    const int th = wave >> 2;
    f32x4 O  = {0.f, 0.f, 0.f, 0.f};
    f32x4 RS = {0.f, 0.f, 0.f, 0.f};
    half8 ONE;
    #pragma unroll
    for (int i = 0; i < 8; ++i) ONE[i] = (_Float16)1.0f;
    const int ro = m + 1;                           // P row (A-row m <-> o-1)
    const int rsw = (ro & 7) << 2;
    const ushort_t* prow = &dpH[ro * DPS];
    const ushort_t* vv_base = vh + ((size_t)bh * 65536
                                    + (size_t)(th * 64 + quad) * 512
                                    + (size_t)(d0 + m) * 8);
    #pragma unroll 4
    for (int i = 0; i < 16; ++i) {
        const int cc = th * 512 + i * 32 + quad * 8;
        half8 ph = mk8(*(const uint2*)&prow[cc ^ rsw],
                       *(const uint2*)&prow[(cc + 4) ^ rsw]);
        half8 vv = *(const half8*)(vv_base + (size_t)i * 2048);
        O  = __builtin_amdgcn_mfma_f32_16x16x32_f16(ph, vv, O, 0, 0, 0);
        RS = __builtin_amdgcn_mfma_f32_16x16x32_f16(ph, ONE, RS, 0, 0, 0);
    }
    // oBuf lives in dpH rows 0 and 17 (never touched by P): br<8 -> row 0,
    // br>=8 -> row 17; XOR swizzle keeps writes/reads ~conflict-free.
    float* const pb = (float*)dpH;
    #define OBUF(br, d) pb[(((br) < 8) ? 0 : (17 * 512)) + ((br) & 7) * 64 \
                           + ((d) ^ (((br) & 7) << 2))]
    if (wave < 4) {
        #pragma unroll
        for (int r = 0; r < 4; ++r) OBUF(quad * 4 + r, d0 + m) = O[r];
    }
    if (wave == 0 && m == 0) {   // lanes 0,16,32,48: publish th=0 rowsums
        float* lsRow = (float*)aux;               // mb is dead now
        #pragma unroll
        for (int r = 0; r < 4; ++r) lsRow[quad * 4 + r] = RS[r];
    }
    __syncthreads();
    if (wave >= 4) {
        const float* lsRow = (const float*)aux;
        #pragma unroll
        for (int r = 0; r < 4; ++r) {
            const int rr = quad * 4 + r;          // o = rr+1, s = s0+rr
            const float lsum = lsRow[rr] + RS[r];
            out[((size_t)bh * S_LEN + s0 + rr) * D_DIM + d0 + m] =
                (O[r] + OBUF(rr, d0 + m)) / lsum;
        }
    }
    #undef OBUF
}

extern "C" void kernel_launch(void* const* d_in, const int* in_sizes, int n_in,
                              void* d_out, int out_size, void* d_ws, size_t ws_size,
                              hipStream_t stream) {
    const float* q      = (const float*)d_in[0];
    const float* k      = (const float*)d_in[1];
    const float* v      = (const float*)d_in[2];
    const int*   mask   = (const int*)d_in[3];
    const float* conv_w = (const float*)d_in[4];
    const float* conv_b = (const float*)d_in[5];
    const float* lin_w  = (const float*)d_in[6];
    const float* lin_b  = (const float*)d_in[7];
    float* out = (float*)d_out;

    char* wsb = (char*)d_ws;
    const size_t MB = 1024 * 1024;
    ushort_t* kh = (ushort_t*)(wsb + 0 * MB);     // 2 MiB
    ushort_t* vh = (ushort_t*)(wsb + 2 * MB);     // 2 MiB
    unsigned* mw = (unsigned*)(wsb + 4 * MB);     // 256 KiB

    prep<<<dim3(1024), 256, 0, stream>>>(k, v, mask, kh, vh, mw);
    fused_qk_conv_av<<<dim3(NSB, NBH), 512, 0, stream>>>(
        q, kh, mw, vh, conv_w, conv_b, lin_w, lin_b, out);
}